// Round 7
// baseline (2763.180 us; speedup 1.0000x reference)
//
#include <hip/hip_runtime.h>

typedef unsigned int u32;
typedef unsigned long long u64;
typedef float f32x2 __attribute__((ext_vector_type(2)));

#define NPB 8192
#define BCL 4
#define MS 2048
#define KN 64
#define OFF_POS   (BCL * MS * 128)            // element offsets into d_out (f32)
#define OFF_BATCH (OFF_POS + BCL * MS * 3)

__device__ inline u64 umax64(u64 a, u64 b) { return a < b ? b : a; }
__device__ inline u32 umax32(u32 a, u32 b) { return a < b ? b : a; }

// packed f32 ops: IEEE-identical per half to v_add_f32 / v_mul_f32 -> bit-exact
__device__ inline f32x2 pk_add(f32x2 a, f32x2 b) {
  f32x2 d;
  asm("v_pk_add_f32 %0, %1, %2" : "=v"(d) : "v"(a), "v"(b));
  return d;
}
__device__ inline f32x2 pk_mul(f32x2 a, f32x2 b) {
  f32x2 d;
  asm("v_pk_mul_f32 %0, %1, %2" : "=v"(d) : "v"(a), "v"(b));
  return d;
}

// wave64 max via DPP (VALU forwarding, no LDS round-trips).
// row_shr 1/2/4/8 -> lane15 of each 16-row holds row max; row_bcast15 merges
// row pairs (lanes 31/63); row_bcast31 merges halves (lane 63 = full max).
__device__ inline u32 wave_max_u32(u32 v) {
  v = umax32(v, (u32)__builtin_amdgcn_update_dpp(0, (int)v, 0x111, 0xf, 0xf, false));
  v = umax32(v, (u32)__builtin_amdgcn_update_dpp(0, (int)v, 0x112, 0xf, 0xf, false));
  v = umax32(v, (u32)__builtin_amdgcn_update_dpp(0, (int)v, 0x114, 0xf, 0xf, false));
  v = umax32(v, (u32)__builtin_amdgcn_update_dpp(0, (int)v, 0x118, 0xf, 0xf, false));
  v = umax32(v, (u32)__builtin_amdgcn_update_dpp(0, (int)v, 0x142, 0xa, 0xf, false));
  v = umax32(v, (u32)__builtin_amdgcn_update_dpp(0, (int)v, 0x143, 0xc, 0xf, false));
  return (u32)__builtin_amdgcn_readlane((int)v, 63);
}

__device__ inline u32 part1by2(u32 x) {   // spread 10 bits -> every 3rd bit
  x &= 0x3ffu;
  x = (x | (x << 16)) & 0x030000FFu;
  x = (x | (x << 8))  & 0x0300F00Fu;
  x = (x | (x << 4))  & 0x030C30C3u;
  x = (x | (x << 2))  & 0x09249249u;
  return x;
}

// ---------------------------------------------------------------------------
// Kernel 1: farthest point sampling with exact spatial pruning + DPP argmax.
// One block/cloud, 1024 thr, 8 pts/thread, Morton-sorted blobs (R6).
// Per iter: two-phase DPP wave max (d2 bits, then ~idx among ties) ==
// lexicographic u64 max -> bit-identical to the R4-R6 butterfly. Wave leaders
// write wmax slots (double-buffered); all threads tree-scan 16 slots after
// ONE barrier. samp/pos_out stores deferred to the end (s_samp in LDS).
// Update skipped via conservative bbox bound (R6, bit-exact).
// ---------------------------------------------------------------------------
__global__ __launch_bounds__(1024) void fps_kernel(
    const float* __restrict__ pos, int* __restrict__ samp,
    float* __restrict__ out) {
  extern __shared__ u64 smem[];   // 64 KB; sort buffer -> wmax[2][16] + s_samp
  int b = blockIdx.x, t = threadIdx.x, lane = t & 63, wv = t >> 6;
  const float* pb = pos + (size_t)b * NPB * 3;

  // ---- 1) Morton keys (30b) | orig idx (13b) ----
  for (int i = t; i < NPB; i += 1024) {
    float xx = pb[i * 3], yy = pb[i * 3 + 1], zz = pb[i * 3 + 2];
    u32 xi = (u32)fminf(fmaxf(xx * 1024.0f, 0.0f), 1023.0f);
    u32 yi = (u32)fminf(fmaxf(yy * 1024.0f, 0.0f), 1023.0f);
    u32 zi = (u32)fminf(fmaxf(zz * 1024.0f, 0.0f), 1023.0f);
    u32 m = (part1by2(zi) << 2) | (part1by2(yi) << 1) | part1by2(xi);
    smem[i] = ((u64)m << 13) | (u32)i;
  }
  // ---- 2) bitonic sort 8192 ----
  for (int k = 2; k <= NPB; k <<= 1) {
    for (int j = k >> 1; j > 0; j >>= 1) {
      __syncthreads();
      for (int i = t; i < NPB; i += 1024) {
        int ix = i ^ j;
        if (ix > i) {
          u64 a = smem[i], c = smem[ix];
          bool up = ((i & k) == 0);
          if ((a > c) == up) { smem[i] = c; smem[ix] = a; }
        }
      }
    }
  }
  __syncthreads();
  // ---- 3) extract my blob (8 consecutive sorted points) ----
  int oi[8];
  #pragma unroll
  for (int i = 0; i < 8; ++i) oi[i] = (int)(smem[8 * t + i] & 0x1FFFu);
  __syncthreads();                 // sort data dead; smem reused below

  u64* wmax = smem;                // [2][16] double-buffered wave maxima
  int* s_samp = (int*)smem + 64;   // 2048 ints (bytes 256..8448)

  // gather coords (one-time scattered, L2-hot) + bbox + tie-break lo words
  f32x2 px[4], py[4], pz[4], mind[4];
  u32 lo[8];
  float bxl = 1e30f, bxh = -1e30f, byl = 1e30f, byh = -1e30f, bzl = 1e30f, bzh = -1e30f;
  #pragma unroll
  for (int j = 0; j < 4; ++j) {
    int iA = oi[2 * j], iB = oi[2 * j + 1];
    float xA = pb[iA * 3], yA = pb[iA * 3 + 1], zA = pb[iA * 3 + 2];
    float xB = pb[iB * 3], yB = pb[iB * 3 + 1], zB = pb[iB * 3 + 2];
    px[j] = f32x2{xA, xB}; py[j] = f32x2{yA, yB}; pz[j] = f32x2{zA, zB};
    lo[2 * j] = ~(u32)iA; lo[2 * j + 1] = ~(u32)iB;
    bxl = fminf(bxl, fminf(xA, xB)); bxh = fmaxf(bxh, fmaxf(xA, xB));
    byl = fminf(byl, fminf(yA, yB)); byh = fmaxf(byh, fmaxf(yA, yB));
    bzl = fminf(bzl, fminf(zA, zB)); bzh = fmaxf(bzh, fmaxf(zA, zB));
  }

  // ---- 4) init distances vs point 0 + initial best key ----
  float cx = pb[0], cy = pb[1], cz = pb[2];
  if (t == 0) s_samp[0] = 0;
  u64 lkey;
  {
    f32x2 mcx = f32x2{-cx, -cx}, mcy = f32x2{-cy, -cy}, mcz = f32x2{-cz, -cz};
    #pragma unroll
    for (int j = 0; j < 4; ++j) {
      f32x2 dx = pk_add(px[j], mcx), dy = pk_add(py[j], mcy), dz = pk_add(pz[j], mcz);
      mind[j] = pk_add(pk_add(pk_mul(dx, dx), pk_mul(dy, dy)), pk_mul(dz, dz));
    }
    u64 k0 = ((u64)__float_as_uint(mind[0].x) << 32) | lo[0];
    u64 k1 = ((u64)__float_as_uint(mind[0].y) << 32) | lo[1];
    u64 k2 = ((u64)__float_as_uint(mind[1].x) << 32) | lo[2];
    u64 k3 = ((u64)__float_as_uint(mind[1].y) << 32) | lo[3];
    u64 k4 = ((u64)__float_as_uint(mind[2].x) << 32) | lo[4];
    u64 k5 = ((u64)__float_as_uint(mind[2].y) << 32) | lo[5];
    u64 k6 = ((u64)__float_as_uint(mind[3].x) << 32) | lo[6];
    u64 k7 = ((u64)__float_as_uint(mind[3].y) << 32) | lo[7];
    lkey = umax64(umax64(umax64(k0, k1), umax64(k2, k3)),
                  umax64(umax64(k4, k5), umax64(k6, k7)));
  }

  for (int it = 1; it < MS; ++it) {
    // two-phase DPP wave argmax == u64 lexicographic max of lkey
    u32 hi = (u32)(lkey >> 32), lo32v = (u32)lkey;
    u32 m = wave_max_u32(hi);
    u32 cand = (hi == m) ? lo32v : 0u;
    u32 c = wave_max_u32(cand);
    if (lane == 0) wmax[((it & 1) << 4) | wv] = ((u64)m << 32) | c;
    __syncthreads();
    const u64* ww = &wmax[(it & 1) << 4];
    u64 a0 = umax64(umax64(ww[0], ww[1]), umax64(ww[2], ww[3]));
    u64 a1 = umax64(umax64(ww[4], ww[5]), umax64(ww[6], ww[7]));
    u64 a2 = umax64(umax64(ww[8], ww[9]), umax64(ww[10], ww[11]));
    u64 a3 = umax64(umax64(ww[12], ww[13]), umax64(ww[14], ww[15]));
    u64 g = umax64(umax64(a0, a1), umax64(a2, a3));
    int win = (int)(~(u32)g) & (NPB - 1);
    float ncx = pb[win * 3], ncy = pb[win * 3 + 1], ncz = pb[win * 3 + 2];
    if (t == 0) s_samp[it] = win;
    // exact-skip test: conservative bbox lower bound vs cached blob max
    float lmax = __uint_as_float((u32)(lkey >> 32));
    float ax = fmaxf(fmaxf(__fsub_rn(bxl, ncx), __fsub_rn(ncx, bxh)), 0.0f);
    float ay = fmaxf(fmaxf(__fsub_rn(byl, ncy), __fsub_rn(ncy, byh)), 0.0f);
    float az = fmaxf(fmaxf(__fsub_rn(bzl, ncz), __fsub_rn(ncz, bzh)), 0.0f);
    float lb2 = (ax * ax + ay * ay + az * az) * 0.9999961853f;  // *(1-2^-18)
    if (lb2 <= lmax) {             // blob may change: do the exact update
      f32x2 mcx = f32x2{-ncx, -ncx}, mcy = f32x2{-ncy, -ncy}, mcz = f32x2{-ncz, -ncz};
      #pragma unroll
      for (int j = 0; j < 4; ++j) {
        f32x2 dx = pk_add(px[j], mcx), dy = pk_add(py[j], mcy), dz = pk_add(pz[j], mcz);
        f32x2 d2 = pk_add(pk_add(pk_mul(dx, dx), pk_mul(dy, dy)), pk_mul(dz, dz));
        mind[j].x = fminf(mind[j].x, d2.x);
        mind[j].y = fminf(mind[j].y, d2.y);
      }
      u64 k0 = ((u64)__float_as_uint(mind[0].x) << 32) | lo[0];
      u64 k1 = ((u64)__float_as_uint(mind[0].y) << 32) | lo[1];
      u64 k2 = ((u64)__float_as_uint(mind[1].x) << 32) | lo[2];
      u64 k3 = ((u64)__float_as_uint(mind[1].y) << 32) | lo[3];
      u64 k4 = ((u64)__float_as_uint(mind[2].x) << 32) | lo[4];
      u64 k5 = ((u64)__float_as_uint(mind[2].y) << 32) | lo[5];
      u64 k6 = ((u64)__float_as_uint(mind[3].x) << 32) | lo[6];
      u64 k7 = ((u64)__float_as_uint(mind[3].y) << 32) | lo[7];
      lkey = umax64(umax64(umax64(k0, k1), umax64(k2, k3)),
                    umax64(umax64(k4, k5), umax64(k6, k7)));
    }
  }
  __syncthreads();
  // ---- 5) deferred global writeback ----
  float* pos_out = out + OFF_POS + (size_t)b * MS * 3;
  float* batch_out = out + OFF_BATCH + (size_t)b * MS;
  for (int m = t; m < MS; m += 1024) {
    int s = s_samp[m];
    samp[b * MS + m] = s;
    pos_out[m * 3] = pb[s * 3];
    pos_out[m * 3 + 1] = pb[s * 3 + 1];
    pos_out[m * 3 + 2] = pb[s * 3 + 2];
    batch_out[m] = (float)b;
  }
}

// ---------------------------------------------------------------------------
// Kernel 2: radius ball + K-nearest-in-ball (lax.top_k semantics). FROZEN.
// ---------------------------------------------------------------------------
__global__ __launch_bounds__(256) void nbr_kernel(
    const float* __restrict__ pos, const int* __restrict__ samp,
    int* __restrict__ nbr) {
  const float R2CUT = (float)(0.2 * 0.2);   // 0x3D23D70A
  int c = blockIdx.x, b = c >> 11, t = threadIdx.x;
  const float* pb = pos + (size_t)b * NPB * 3;
  int s = samp[c] & (NPB - 1);
  float cx = pb[s * 3], cy = pb[s * 3 + 1], cz = pb[s * 3 + 2];
  __shared__ u64 cand[512];
  __shared__ int cnt;
  if (t == 0) cnt = 0;
  __syncthreads();
  for (int j = t; j < NPB; j += 256) {
    float dx = __fsub_rn(pb[j * 3], cx);
    float dy = __fsub_rn(pb[j * 3 + 1], cy);
    float dz = __fsub_rn(pb[j * 3 + 2], cz);
    float d2 = __fadd_rn(__fadd_rn(__fmul_rn(dx, dx), __fmul_rn(dy, dy)), __fmul_rn(dz, dz));
    if (d2 <= R2CUT) {
      int sl = atomicAdd(&cnt, 1);
      if (sl < 512) cand[sl] = ((u64)__float_as_uint(d2) << 32) | (u32)j;
    }
  }
  __syncthreads();
  int n = cnt; if (n > 512) n = 512;
  for (int i = t; i < 512; i += 256) if (i >= n) cand[i] = ~0ull;
  __syncthreads();
  for (int k = 2; k <= 512; k <<= 1) {
    for (int j = k >> 1; j > 0; j >>= 1) {
      for (int i = t; i < 512; i += 256) {
        int ix = i ^ j;
        if (ix > i) {
          u64 a = cand[i], bb = cand[ix];
          bool up = ((i & k) == 0);
          if ((a > bb) == up) { cand[i] = bb; cand[ix] = a; }
        }
      }
      __syncthreads();
    }
  }
  if (t < KN) nbr[(size_t)c * KN + t] = (t < n) ? (int)(cand[t] & 0xffffffffu) : -1;
}

// ---------------------------------------------------------------------------
// Kernel 3: gather -> f32 VALU MLP -> masked max-pool. FROZEN (absmax 0.0).
// ---------------------------------------------------------------------------
__global__ __launch_bounds__(256) void mlp_kernel(
    const float* __restrict__ x, const float* __restrict__ pos,
    const int* __restrict__ samp, const int* __restrict__ nbr,
    const float* __restrict__ W1, const float* __restrict__ b1,
    const float* __restrict__ W2, const float* __restrict__ b2,
    const float* __restrict__ W3, const float* __restrict__ b3,
    float* __restrict__ out) {
  int c = blockIdx.x, b = c >> 11, t = threadIdx.x;

  __shared__ float s_feat[64][68];
  __shared__ float s_h[64][68];
  __shared__ float s_w[68][64];
  __shared__ float s_mask[64];
  __shared__ float s_red[4][64];

  const int* nb = nbr + (size_t)c * KN;

  {
    int r = t >> 2, q = t & 3;
    int j = nb[r];
    bool valid = (j >= 0 && j < NPB);
    size_t jj = valid ? (size_t)j : 0;
    const float4* xp = (const float4*)(x + ((size_t)b * NPB + jj) * 64 + q * 16);
    float4 v[4];
    for (int i = 0; i < 4; ++i) v[i] = xp[i];
    for (int i = 0; i < 4; ++i) {
      s_feat[r][q * 16 + i * 4 + 0] = valid ? v[i].x : 0.0f;
      s_feat[r][q * 16 + i * 4 + 1] = valid ? v[i].y : 0.0f;
      s_feat[r][q * 16 + i * 4 + 2] = valid ? v[i].z : 0.0f;
      s_feat[r][q * 16 + i * 4 + 3] = valid ? v[i].w : 0.0f;
    }
  }
  if (t < 64) {
    int r = t;
    int j = nb[r];
    bool valid = (j >= 0 && j < NPB);
    s_mask[r] = valid ? 0.0f : -__builtin_inff();
    int s = samp[c] & (NPB - 1);
    size_t jj = valid ? (size_t)j : (size_t)s;
    for (int d = 0; d < 3; ++d) {
      float pj = pos[((size_t)b * NPB + jj) * 3 + d];
      float pc = pos[((size_t)b * NPB + s) * 3 + d];
      s_feat[r][64 + d] = __fsub_rn(pj, pc);
    }
  }
  for (int idx = t; idx < 67 * 64; idx += 256)
    s_w[idx >> 6][idx & 63] = W1[idx];
  __syncthreads();

  {
    int r = t >> 2, n0 = (t & 3) * 16;
    float acc[16];
    for (int j = 0; j < 16; ++j) acc[j] = b1[n0 + j];
    for (int k = 0; k < 67; ++k) {
      float f = s_feat[r][k];
      for (int j = 0; j < 16; ++j) acc[j] += f * s_w[k][n0 + j];
    }
    __syncthreads();
    for (int j = 0; j < 16; ++j) s_h[r][n0 + j] = fmaxf(acc[j], 0.0f);
  }
  for (int idx = t; idx < 64 * 64; idx += 256)
    s_w[idx >> 6][idx & 63] = W2[idx];
  __syncthreads();

  {
    int r = t >> 2, n0 = (t & 3) * 16;
    float acc[16];
    for (int j = 0; j < 16; ++j) acc[j] = b2[n0 + j];
    for (int k = 0; k < 64; ++k) {
      float f = s_h[r][k];
      for (int j = 0; j < 16; ++j) acc[j] += f * s_w[k][n0 + j];
    }
    __syncthreads();
    for (int j = 0; j < 16; ++j) s_feat[r][n0 + j] = fmaxf(acc[j], 0.0f);
  }
  __syncthreads();

  for (int h = 0; h < 2; ++h) {
    for (int idx = t; idx < 64 * 64; idx += 256)
      s_w[idx >> 6][idx & 63] = W3[(size_t)(idx >> 6) * 128 + h * 64 + (idx & 63)];
    __syncthreads();
    int n = t & 63, rg = t >> 6;
    float acc[16];
    float bias = b3[h * 64 + n];
    for (int rr = 0; rr < 16; ++rr) acc[rr] = bias;
    for (int k = 0; k < 64; ++k) {
      float w = s_w[k][n];
      for (int rr = 0; rr < 16; ++rr) acc[rr] += s_feat[rg * 16 + rr][k] * w;
    }
    float m = -__builtin_inff();
    for (int rr = 0; rr < 16; ++rr)
      m = fmaxf(m, fmaxf(acc[rr], 0.0f) + s_mask[rg * 16 + rr]);
    s_red[rg][n] = m;
    __syncthreads();
    if (t < 64) {
      float mm = fmaxf(fmaxf(s_red[0][t], s_red[1][t]), fmaxf(s_red[2][t], s_red[3][t]));
      out[(size_t)c * 128 + h * 64 + t] = mm;
    }
    __syncthreads();
  }
}

// ---------------------------------------------------------------------------
extern "C" void kernel_launch(void* const* d_in, const int* in_sizes, int n_in,
                              void* d_out, int out_size, void* d_ws, size_t ws_size,
                              hipStream_t stream) {
  const float* x   = (const float*)d_in[0];
  const float* pos = (const float*)d_in[1];
  // d_in[2] = batch (int32), unused
  const float* W1 = (const float*)d_in[3];
  const float* b1 = (const float*)d_in[4];
  const float* W2 = (const float*)d_in[5];
  const float* b2 = (const float*)d_in[6];
  const float* W3 = (const float*)d_in[7];
  const float* b3 = (const float*)d_in[8];

  float* out = (float*)d_out;
  int* samp = (int*)d_ws;            // [8192]
  int* nbr = samp + BCL * MS;        // [8192*64]

  fps_kernel<<<BCL, 1024, NPB * sizeof(u64), stream>>>(pos, samp, out);
  nbr_kernel<<<BCL * MS, 256, 0, stream>>>(pos, samp, nbr);
  mlp_kernel<<<BCL * MS, 256, 0, stream>>>(x, pos, samp, nbr,
                                           W1, b1, W2, b2, W3, b3, out);
}